// Round 1
// baseline (192.085 us; speedup 1.0000x reference)
//
#include <hip/hip_runtime.h>
#include <hip/hip_bf16.h>
#include <stdint.h>

#define B_N   16384
#define D_N   64
#define L_N   63
#define H_N   128

typedef unsigned int   u32;
typedef unsigned short u16;
typedef __attribute__((ext_vector_type(8))) __bf16 bf16x8;
typedef __attribute__((ext_vector_type(4))) float  f32x4;

// f32 -> bf16 round-to-nearest-even (manual, no __bf16 scalar ops needed)
__device__ __forceinline__ u16 f2b(float f){
  u32 u = __builtin_bit_cast(u32, f);
  u += 0x7fffu + ((u >> 16) & 1u);
  return (u16)(u >> 16);
}
// fast tanh: 1 - 2/(e^{2x}+1); saturates correctly for |x| large
__device__ __forceinline__ float tanh_fast(float x){
  float e = __expf(2.0f * x);
  return 1.0f - __fdividef(2.0f, e + 1.0f);
}

// ---- weight conversion: W1[l][d][n] (masked d<=l) -> W1T[l][n][d_pad64] bf16 ----
__global__ void k_conv_w1(const float* __restrict__ W1, u16* __restrict__ out){
  __shared__ u16 t[128*64];
  const int l = blockIdx.x, tid = threadIdx.x;
  #pragma unroll
  for (int i = 0; i < 32; ++i) t[i*256 + tid] = 0;
  __syncthreads();
  for (int i = 0; i < 32; ++i){
    int idx = i*256 + tid;              // idx = d*128 + n  (coalesced read)
    if (idx < 63*128){
      int d = idx >> 7, n = idx & 127;
      if (d <= l) t[n*64 + d] = f2b(W1[(l*63 + d)*128 + n]);
    }
  }
  __syncthreads();
  uint4* o = (uint4*)(out + l*(128*64));
  const uint4* s4 = (const uint4*)t;
  #pragma unroll
  for (int i = 0; i < 4; ++i) o[i*256 + tid] = s4[i*256 + tid];
}

// ---- W2[l][h][k] -> W2T[l][k][h] bf16 ----
__global__ void k_conv_w2(const float* __restrict__ W2, u16* __restrict__ out){
  __shared__ u16 t[128*128];
  const int l = blockIdx.x, tid = threadIdx.x;
  #pragma unroll
  for (int i = 0; i < 64; ++i){
    int idx = i*256 + tid;              // idx = h*128 + k  (coalesced read)
    int h = idx >> 7, k = idx & 127;
    t[k*128 + h] = f2b(W2[l*16384 + idx]);
  }
  __syncthreads();
  uint4* o = (uint4*)(out + l*(128*128));
  const uint4* s4 = (const uint4*)t;
  #pragma unroll
  for (int i = 0; i < 8; ++i) o[i*256 + tid] = s4[i*256 + tid];
}

// ---- x f32 -> bf16 ----
__global__ void k_conv_x(const float* __restrict__ x, u16* __restrict__ out){
  int idx = blockIdx.x*256 + threadIdx.x;     // covers B_N*D_N/4 exactly
  float4 v = ((const float4*)x)[idx];
  ushort4 r;
  r.x = f2b(v.x); r.y = f2b(v.y); r.z = f2b(v.z); r.w = f2b(v.w);
  ((ushort4*)out)[idx] = r;
}

// ---- main fused MLP kernel: one block = (64 batch rows) x (one layer l) ----
// LDS: [0,8192)   x tile  [64 b][64 d] bf16, XOR-swizzled rows
//      [8192,24576) h1    [64 b][128 h] bf16, XOR-swizzled rows
//      [24576,26624) stage-3 partials float[4][64][2]
__global__ __launch_bounds__(256, 2)
void k_main(const u16* __restrict__ W1T, const u16* __restrict__ W2T,
            const u16* __restrict__ xbf, const float* __restrict__ b1,
            const float* __restrict__ b2, const float* __restrict__ W3,
            const float* __restrict__ b3, float* __restrict__ mu,
            float* __restrict__ alpha)
{
  __shared__ __align__(16) char lds[26624];
  const int tid = threadIdx.x;
  const int l  = blockIdx.y;
  const int bx = blockIdx.x;
  const int wv = tid >> 6;      // wave 0..3, owns M-tiles {2wv, 2wv+1}
  const int ln = tid & 63;
  const int c  = ln & 15;       // fragment row/col-in-tile
  const int g  = ln >> 4;       // k-group / D-row group

  // stage x tile into LDS (swizzled)
  {
    const uint4* xg = (const uint4*)(xbf + (size_t)bx * 64 * 64);
    #pragma unroll
    for (int i = 0; i < 2; ++i){
      int q = tid*2 + i;                 // chunk 0..511
      int row = q >> 3, cq = q & 7;
      uint4 v = xg[q];
      *(uint4*)(lds + row*128 + ((cq*16) ^ ((row&7)<<4))) = v;
    }
  }

  const u16* w1p = W1T + l * (128*64);
  const u16* w2p = W2T + l * (128*128);

  // stage-1 A-fragments from global (own M-tiles only; contiguous 16B)
  bf16x8 a1[2][2];
  #pragma unroll
  for (int m = 0; m < 2; ++m)
    #pragma unroll
    for (int s = 0; s < 2; ++s)
      a1[m][s] = *(const bf16x8*)(w1p + ((2*wv+m)*16 + c)*64 + s*32 + g*8);

  __syncthreads();

  // ---- stage 1: h1T[h][b] = tanh(W1T . xT + b1) ----
  f32x4 acc1[2][4] = {};
  #pragma unroll
  for (int s = 0; s < 2; ++s){
    bf16x8 bfr[4];
    #pragma unroll
    for (int bt = 0; bt < 4; ++bt){
      int b = bt*16 + c;
      bfr[bt] = *(const bf16x8*)(lds + b*128 + ((s*64 + g*16) ^ ((b&7)<<4)));
    }
    #pragma unroll
    for (int m = 0; m < 2; ++m)
      #pragma unroll
      for (int bt = 0; bt < 4; ++bt)
        acc1[m][bt] = __builtin_amdgcn_mfma_f32_16x16x32_bf16(a1[m][s], bfr[bt], acc1[m][bt], 0, 0, 0);
  }

  // epilogue 1: bias + tanh, pack 4 bf16, packed ds_write_b64 (swizzled)
  #pragma unroll
  for (int m = 0; m < 2; ++m){
    int h0 = (2*wv+m)*16 + g*4;
    float bv0 = b1[l*128 + h0 + 0], bv1 = b1[l*128 + h0 + 1];
    float bv2 = b1[l*128 + h0 + 2], bv3 = b1[l*128 + h0 + 3];
    #pragma unroll
    for (int bt = 0; bt < 4; ++bt){
      u32 p0 = (u32)f2b(tanh_fast(acc1[m][bt][0] + bv0))
             | ((u32)f2b(tanh_fast(acc1[m][bt][1] + bv1)) << 16);
      u32 p1 = (u32)f2b(tanh_fast(acc1[m][bt][2] + bv2))
             | ((u32)f2b(tanh_fast(acc1[m][bt][3] + bv3)) << 16);
      int b = bt*16 + c;
      *(uint2*)(lds + 8192 + b*256 + ((h0*2) ^ ((b&7)<<4))) = make_uint2(p0, p1);
    }
  }
  __syncthreads();

  // ---- stage 2: h2T[k][b] = tanh(W2T . h1T + b2) ----
  f32x4 acc2[2][4] = {};
  #pragma unroll
  for (int s = 0; s < 4; ++s){
    bf16x8 bfr[4];
    #pragma unroll
    for (int bt = 0; bt < 4; ++bt){
      int b = bt*16 + c;
      bfr[bt] = *(const bf16x8*)(lds + 8192 + b*256 + ((s*64 + g*16) ^ ((b&7)<<4)));
    }
    #pragma unroll
    for (int m = 0; m < 2; ++m){
      bf16x8 a = *(const bf16x8*)(w2p + ((2*wv+m)*16 + c)*128 + s*32 + g*8);
      #pragma unroll
      for (int bt = 0; bt < 4; ++bt)
        acc2[m][bt] = __builtin_amdgcn_mfma_f32_16x16x32_bf16(a, bfr[bt], acc2[m][bt], 0, 0, 0);
    }
  }

  // epilogue 2 + stage 3: tanh, dot with W3[128][2], reduce over k
  float part[4][2] = {{0.f,0.f},{0.f,0.f},{0.f,0.f},{0.f,0.f}};
  #pragma unroll
  for (int m = 0; m < 2; ++m){
    int k0 = (2*wv+m)*16 + g*4;
    float bv[4], w30[4], w31[4];
    #pragma unroll
    for (int r = 0; r < 4; ++r){
      bv[r] = b2[l*128 + k0 + r];
      float2 w3v = ((const float2*)W3)[l*128 + k0 + r];
      w30[r] = w3v.x; w31[r] = w3v.y;
    }
    #pragma unroll
    for (int bt = 0; bt < 4; ++bt)
      #pragma unroll
      for (int r = 0; r < 4; ++r){
        float h2 = tanh_fast(acc2[m][bt][r] + bv[r]);
        part[bt][0] = fmaf(h2, w30[r], part[bt][0]);
        part[bt][1] = fmaf(h2, w31[r], part[bt][1]);
      }
  }
  // reduce across the 4 k-groups (lanes +-16, +-32)
  #pragma unroll
  for (int bt = 0; bt < 4; ++bt)
    #pragma unroll
    for (int o = 0; o < 2; ++o){
      float v = part[bt][o];
      v += __shfl_xor(v, 16, 64);
      v += __shfl_xor(v, 32, 64);
      part[bt][o] = v;
    }
  float* sc = (float*)(lds + 24576);
  if (g == 0){
    #pragma unroll
    for (int bt = 0; bt < 4; ++bt){
      sc[(wv*64 + bt*16 + c)*2 + 0] = part[bt][0];
      sc[(wv*64 + bt*16 + c)*2 + 1] = part[bt][1];
    }
  }
  __syncthreads();
  if (tid < 128){
    int b = tid >> 1, o = tid & 1;
    float sum = sc[b*2+o] + sc[(64+b)*2+o] + sc[(128+b)*2+o] + sc[(192+b)*2+o]
              + b3[l*2 + o];
    int row = bx*64 + b;
    if (o == 0) mu[row*64 + l + 1]    = sum;
    else        alpha[row*64 + l + 1] = sum;
  }
}

// ---- finalize: z = (x-mu)*exp(-alpha), reversed; logdet = -sum(alpha) ----
__global__ void k_fin(const float* __restrict__ x, const float* __restrict__ mu,
                      const float* __restrict__ alpha, const float* __restrict__ ip,
                      float* __restrict__ out)
{
  int row = blockIdx.x*4 + (threadIdx.x >> 6);
  int d   = threadIdx.x & 63;
  float xv = x[row*64 + d];
  float m  = (d == 0) ? ip[0] : mu[row*64 + d];
  float a  = (d == 0) ? ip[1] : alpha[row*64 + d];
  float z  = (xv - m) * __expf(-a);
  out[row*64 + 63 - d] = z;
  float s = a;
  #pragma unroll
  for (int off = 32; off; off >>= 1) s += __shfl_xor(s, off, 64);
  if (d == 0) out[B_N*D_N + row] = -s;
}

extern "C" void kernel_launch(void* const* d_in, const int* in_sizes, int n_in,
                              void* d_out, int out_size, void* d_ws, size_t ws_size,
                              hipStream_t stream)
{
  const float* x  = (const float*)d_in[0];
  const float* W1 = (const float*)d_in[1];
  const float* b1 = (const float*)d_in[2];
  const float* W2 = (const float*)d_in[3];
  const float* b2 = (const float*)d_in[4];
  const float* W3 = (const float*)d_in[5];
  const float* b3 = (const float*)d_in[6];
  const float* ip = (const float*)d_in[7];

  char* ws = (char*)d_ws;
  // layout: W1T 1MB | W2T 2MB | xbf 2MB | mu 4MB | alpha 4MB  (13.625 MB total)
  u16*   w1t  = (u16*)(ws);
  u16*   w2t  = (u16*)(ws + 1048576);
  u16*   xbf  = (u16*)(ws + 1048576 + 2097152);
  float* mu   = (float*)(ws + 5242880);
  float* alph = (float*)(ws + 9437184);
  if (ws_size < 13631488) return;  // would corrupt; fail visibly instead

  k_conv_w1<<<L_N, 256, 0, stream>>>(W1, w1t);
  k_conv_w2<<<L_N, 256, 0, stream>>>(W2, w2t);
  k_conv_x<<<(B_N*D_N/4)/256, 256, 0, stream>>>(x, xbf);

  dim3 grid(B_N/64, L_N);
  k_main<<<grid, 256, 0, stream>>>(w1t, w2t, xbf, b1, b2, W3, b3, mu, alph);

  k_fin<<<B_N/4, 256, 0, stream>>>(x, mu, alph, ip, (float*)d_out);
}

// Round 2
// 148.823 us; speedup vs baseline: 1.2907x; 1.2907x over previous
//
#include <hip/hip_runtime.h>
#include <hip/hip_bf16.h>
#include <stdint.h>

#define B_N   16384
#define D_N   64
#define L_N   63
#define H_N   128
#define K2LOG2E 2.8853900817779268f   // 2*log2(e)

typedef unsigned int   u32;
typedef unsigned short u16;
typedef __attribute__((ext_vector_type(8))) __bf16 bf16x8;
typedef __attribute__((ext_vector_type(4))) float  f32x4;

// f32 -> bf16 round-to-nearest-even (used only in one-shot conv kernels)
__device__ __forceinline__ u16 f2b(float f){
  u32 u = __builtin_bit_cast(u32, f);
  u += 0x7fffu + ((u >> 16) & 1u);
  return (u16)(u >> 16);
}
// pack two f32 -> bf16x2 in one instruction
__device__ __forceinline__ u32 pk_bf16(float lo, float hi){
  u32 r;
  asm("v_cvt_pk_bf16_f32 %0, %1, %2" : "=v"(r) : "v"(lo), "v"(hi));
  return r;
}
// tanh(acc + b) where bb = b*K2LOG2E is pre-scaled: 5 VALU ops, saturation-safe
__device__ __forceinline__ float tanh_b(float acc, float bb){
  float t = __builtin_amdgcn_exp2f(fmaf(acc, K2LOG2E, bb));
  float r = __builtin_amdgcn_rcpf(t + 1.0f);
  return fmaf(-2.0f, r, 1.0f);
}

// ---- weight conversion: W1[l][d][n] (masked d<=l) -> W1T[l][n][d_pad64] bf16 ----
__global__ void k_conv_w1(const float* __restrict__ W1, u16* __restrict__ out){
  __shared__ u16 t[128*64];
  const int l = blockIdx.x, tid = threadIdx.x;
  #pragma unroll
  for (int i = 0; i < 32; ++i) t[i*256 + tid] = 0;
  __syncthreads();
  for (int i = 0; i < 32; ++i){
    int idx = i*256 + tid;              // idx = d*128 + n  (coalesced read)
    if (idx < 63*128){
      int d = idx >> 7, n = idx & 127;
      if (d <= l) t[n*64 + d] = f2b(W1[(l*63 + d)*128 + n]);
    }
  }
  __syncthreads();
  uint4* o = (uint4*)(out + l*(128*64));
  const uint4* s4 = (const uint4*)t;
  #pragma unroll
  for (int i = 0; i < 4; ++i) o[i*256 + tid] = s4[i*256 + tid];
}

// ---- W2[l][h][k] -> W2T[l][k][h] bf16 ----
__global__ void k_conv_w2(const float* __restrict__ W2, u16* __restrict__ out){
  __shared__ u16 t[128*128];
  const int l = blockIdx.x, tid = threadIdx.x;
  #pragma unroll
  for (int i = 0; i < 64; ++i){
    int idx = i*256 + tid;              // idx = h*128 + k  (coalesced read)
    int h = idx >> 7, k = idx & 127;
    t[k*128 + h] = f2b(W2[l*16384 + idx]);
  }
  __syncthreads();
  uint4* o = (uint4*)(out + l*(128*128));
  const uint4* s4 = (const uint4*)t;
  #pragma unroll
  for (int i = 0; i < 8; ++i) o[i*256 + tid] = s4[i*256 + tid];
}

// ---- x f32 -> bf16 ----
__global__ void k_conv_x(const float* __restrict__ x, u16* __restrict__ out){
  int idx = blockIdx.x*256 + threadIdx.x;     // covers B_N*D_N/4 exactly
  float4 v = ((const float4*)x)[idx];
  ushort4 r;
  r.x = f2b(v.x); r.y = f2b(v.y); r.z = f2b(v.z); r.w = f2b(v.w);
  ((ushort4*)out)[idx] = r;
}

// ---- main fused MLP kernel: one block = (64 batch rows) x (one layer l) ----
// LDS: [0,8192)    x tile [64 b][64 d] bf16, XOR-swizzled rows
//      [8192,24576) h1    [64 b][128 h] bf16, XOR-swizzled rows
//      [24576,26624) stage-3 partials float[4][64][2]
__global__ __launch_bounds__(256, 2)
void k_main(const u16* __restrict__ W1T, const u16* __restrict__ W2T,
            const u16* __restrict__ xbf, const float* __restrict__ b1,
            const float* __restrict__ b2, const float* __restrict__ W3,
            const float* __restrict__ b3, float* __restrict__ mu,
            float* __restrict__ alpha)
{
  __shared__ __align__(16) char lds[26624];
  const int tid = threadIdx.x;
  const int l  = blockIdx.y;
  const int bx = blockIdx.x;
  const int wv = tid >> 6;      // wave 0..3, owns M-tiles {2wv, 2wv+1}
  const int ln = tid & 63;
  const int c  = ln & 15;       // fragment row/col-in-tile
  const int g  = ln >> 4;       // k-group / D-row group

  // stage x tile into LDS (swizzled)
  {
    const uint4* xg = (const uint4*)(xbf + (size_t)bx * 64 * 64);
    #pragma unroll
    for (int i = 0; i < 2; ++i){
      int q = tid*2 + i;                 // chunk 0..511
      int row = q >> 3, cq = q & 7;
      uint4 v = xg[q];
      *(uint4*)(lds + row*128 + ((cq*16) ^ ((row&7)<<4))) = v;
    }
  }

  const u16* w1p = W1T + l * (128*64);
  const u16* w2p = W2T + l * (128*128);

  // stage-1 A-fragments from global (own M-tiles only; contiguous 16B)
  bf16x8 a1[2][2];
  #pragma unroll
  for (int m = 0; m < 2; ++m)
    #pragma unroll
    for (int s = 0; s < 2; ++s)
      a1[m][s] = *(const bf16x8*)(w1p + ((2*wv+m)*16 + c)*64 + s*32 + g*8);

  // pre-scaled biases for this thread's rows: rows h0 = (2wv+m)*16 + g*4 + r
  float bb1[2][4], bb2[2][4], w30[2][4], w31[2][4];
  #pragma unroll
  for (int m = 0; m < 2; ++m){
    int h0 = (2*wv+m)*16 + g*4;
    #pragma unroll
    for (int r = 0; r < 4; ++r){
      bb1[m][r] = b1[l*128 + h0 + r] * K2LOG2E;
      bb2[m][r] = b2[l*128 + h0 + r] * K2LOG2E;
      float2 w3v = ((const float2*)W3)[l*128 + h0 + r];
      w30[m][r] = w3v.x; w31[m][r] = w3v.y;
    }
  }

  __syncthreads();

  // ---- stage 1: h1T[h][b] = tanh(W1T . xT + b1) ----
  f32x4 acc1[2][4] = {};
  #pragma unroll
  for (int s = 0; s < 2; ++s){
    bf16x8 bfr[4];
    #pragma unroll
    for (int bt = 0; bt < 4; ++bt){
      int b = bt*16 + c;
      bfr[bt] = *(const bf16x8*)(lds + b*128 + ((s*64 + g*16) ^ ((b&7)<<4)));
    }
    #pragma unroll
    for (int m = 0; m < 2; ++m)
      #pragma unroll
      for (int bt = 0; bt < 4; ++bt)
        acc1[m][bt] = __builtin_amdgcn_mfma_f32_16x16x32_bf16(a1[m][s], bfr[bt], acc1[m][bt], 0, 0, 0);
  }

  // epilogue 1: tanh(acc+b1) fused, pack via v_cvt_pk_bf16_f32, ds_write_b64
  #pragma unroll
  for (int m = 0; m < 2; ++m){
    int h0 = (2*wv+m)*16 + g*4;
    #pragma unroll
    for (int bt = 0; bt < 4; ++bt){
      float y0 = tanh_b(acc1[m][bt][0], bb1[m][0]);
      float y1 = tanh_b(acc1[m][bt][1], bb1[m][1]);
      float y2 = tanh_b(acc1[m][bt][2], bb1[m][2]);
      float y3 = tanh_b(acc1[m][bt][3], bb1[m][3]);
      u32 p0 = pk_bf16(y0, y1);
      u32 p1 = pk_bf16(y2, y3);
      int b = bt*16 + c;
      *(uint2*)(lds + 8192 + b*256 + ((h0*2) ^ ((b&7)<<4))) = make_uint2(p0, p1);
    }
  }
  __syncthreads();

  // ---- stage 2: h2T[k][b] = tanh(W2T . h1T + b2) ----
  f32x4 acc2[2][4] = {};
  #pragma unroll
  for (int s = 0; s < 4; ++s){
    bf16x8 bfr[4];
    #pragma unroll
    for (int bt = 0; bt < 4; ++bt){
      int b = bt*16 + c;
      bfr[bt] = *(const bf16x8*)(lds + 8192 + b*256 + ((s*64 + g*16) ^ ((b&7)<<4)));
    }
    #pragma unroll
    for (int m = 0; m < 2; ++m){
      bf16x8 a = *(const bf16x8*)(w2p + ((2*wv+m)*16 + c)*128 + s*32 + g*8);
      #pragma unroll
      for (int bt = 0; bt < 4; ++bt)
        acc2[m][bt] = __builtin_amdgcn_mfma_f32_16x16x32_bf16(a, bfr[bt], acc2[m][bt], 0, 0, 0);
    }
  }

  // epilogue 2 + stage 3: tanh(acc+b2), dot with W3[128][2], reduce over k
  float part[4][2] = {{0.f,0.f},{0.f,0.f},{0.f,0.f},{0.f,0.f}};
  #pragma unroll
  for (int m = 0; m < 2; ++m){
    #pragma unroll
    for (int bt = 0; bt < 4; ++bt)
      #pragma unroll
      for (int r = 0; r < 4; ++r){
        float h2 = tanh_b(acc2[m][bt][r], bb2[m][r]);
        part[bt][0] = fmaf(h2, w30[m][r], part[bt][0]);
        part[bt][1] = fmaf(h2, w31[m][r], part[bt][1]);
      }
  }
  // reduce across the 4 k-groups (lanes +-16, +-32)
  #pragma unroll
  for (int bt = 0; bt < 4; ++bt)
    #pragma unroll
    for (int o = 0; o < 2; ++o){
      float v = part[bt][o];
      v += __shfl_xor(v, 16, 64);
      v += __shfl_xor(v, 32, 64);
      part[bt][o] = v;
    }
  float* sc = (float*)(lds + 24576);
  if (g == 0){
    #pragma unroll
    for (int bt = 0; bt < 4; ++bt){
      sc[(wv*64 + bt*16 + c)*2 + 0] = part[bt][0];
      sc[(wv*64 + bt*16 + c)*2 + 1] = part[bt][1];
    }
  }
  __syncthreads();
  if (tid < 128){
    int b = tid >> 1, o = tid & 1;
    float sum = sc[b*2+o] + sc[(64+b)*2+o] + sc[(128+b)*2+o] + sc[(192+b)*2+o]
              + b3[l*2 + o];
    int row = bx*64 + b;
    if (o == 0) mu[row*64 + l + 1]    = sum;
    else        alpha[row*64 + l + 1] = sum;
  }
}

// ---- finalize: z = (x-mu)*exp(-alpha), reversed; logdet = -sum(alpha) ----
__global__ void k_fin(const float* __restrict__ x, const float* __restrict__ mu,
                      const float* __restrict__ alpha, const float* __restrict__ ip,
                      float* __restrict__ out)
{
  int row = blockIdx.x*4 + (threadIdx.x >> 6);
  int d   = threadIdx.x & 63;
  float xv = x[row*64 + d];
  float m  = (d == 0) ? ip[0] : mu[row*64 + d];
  float a  = (d == 0) ? ip[1] : alpha[row*64 + d];
  float z  = (xv - m) * __expf(-a);
  out[row*64 + 63 - d] = z;
  float s = a;
  #pragma unroll
  for (int off = 32; off; off >>= 1) s += __shfl_xor(s, off, 64);
  if (d == 0) out[B_N*D_N + row] = -s;
}

extern "C" void kernel_launch(void* const* d_in, const int* in_sizes, int n_in,
                              void* d_out, int out_size, void* d_ws, size_t ws_size,
                              hipStream_t stream)
{
  const float* x  = (const float*)d_in[0];
  const float* W1 = (const float*)d_in[1];
  const float* b1 = (const float*)d_in[2];
  const float* W2 = (const float*)d_in[3];
  const float* b2 = (const float*)d_in[4];
  const float* W3 = (const float*)d_in[5];
  const float* b3 = (const float*)d_in[6];
  const float* ip = (const float*)d_in[7];

  char* ws = (char*)d_ws;
  // layout: W1T 1MB | W2T 2MB | xbf 2MB | mu 4MB | alpha 4MB  (13.625 MB total)
  u16*   w1t  = (u16*)(ws);
  u16*   w2t  = (u16*)(ws + 1048576);
  u16*   xbf  = (u16*)(ws + 1048576 + 2097152);
  float* mu   = (float*)(ws + 5242880);
  float* alph = (float*)(ws + 9437184);
  if (ws_size < 13631488) return;  // would corrupt; fail visibly instead

  k_conv_w1<<<L_N, 256, 0, stream>>>(W1, w1t);
  k_conv_w2<<<L_N, 256, 0, stream>>>(W2, w2t);
  k_conv_x<<<(B_N*D_N/4)/256, 256, 0, stream>>>(x, xbf);

  dim3 grid(B_N/64, L_N);
  k_main<<<grid, 256, 0, stream>>>(w1t, w2t, xbf, b1, b2, W3, b3, mu, alph);

  k_fin<<<B_N/4, 256, 0, stream>>>(x, mu, alph, ip, (float*)d_out);
}